// Round 6
// baseline (132.663 us; speedup 1.0000x reference)
//
#include <hip/hip_runtime.h>

typedef __bf16 bf16;
typedef float f32x4 __attribute__((ext_vector_type(4)));
typedef bf16 bf16x4 __attribute__((ext_vector_type(4)));
typedef bf16 bf16x8 __attribute__((ext_vector_type(8)));

#define MFMA16(a, b, c) __builtin_amdgcn_mfma_f32_16x16x32_bf16((a), (b), (c), 0, 0, 0)

__device__ __forceinline__ f32x4 zero4() {
    f32x4 z; z[0] = 0.f; z[1] = 0.f; z[2] = 0.f; z[3] = 0.f; return z;
}
// async global -> LDS, 16B/lane. LDS dest = wave-uniform base + lane*16.
__device__ __forceinline__ void gl_lds16(const bf16* g, bf16* l) {
    __builtin_amdgcn_global_load_lds(
        (const __attribute__((address_space(1))) void*)g,
        (__attribute__((address_space(3))) void*)l, 16, 0, 0);
}

// ---------------- prep: f32 -> bf16 elementwise ----------------
__global__ __launch_bounds__(256) void conv_k(const float* __restrict__ src,
                                              bf16* __restrict__ dst, int n)
{
    const int i = (blockIdx.x * 256 + threadIdx.x) * 8;
    if (i >= n) return;
    const float4 a = *(const float4*)(src + i);
    const float4 b = *(const float4*)(src + i + 4);
    bf16x8 o;
    o[0] = (bf16)a.x; o[1] = (bf16)a.y; o[2] = (bf16)a.z; o[3] = (bf16)a.w;
    o[4] = (bf16)b.x; o[5] = (bf16)b.y; o[6] = (bf16)b.z; o[7] = (bf16)b.w;
    *(bf16x8*)(dst + i) = o;
}

// ---------------- prep: transpose+convert w [K][N] f32 -> wT [N][K] bf16 ----------------
__global__ __launch_bounds__(256) void transp_k(const float* __restrict__ src,
                                                bf16* __restrict__ dst, int K, int N)
{
    __shared__ bf16 Ls[64][72];
    const int tid = threadIdx.x;
    const int k0 = blockIdx.y << 6;
    const int n0 = blockIdx.x << 6;
    #pragma unroll
    for (int it = 0; it < 4; ++it) {
        const int lin = (it << 10) + (tid << 2);
        const int r = lin >> 6, c = lin & 63;
        const float4 v = *(const float4*)(src + (size_t)(k0 + r) * N + n0 + c);
        bf16x4 o; o[0] = (bf16)v.x; o[1] = (bf16)v.y; o[2] = (bf16)v.z; o[3] = (bf16)v.w;
        *(bf16x4*)&Ls[r][c] = o;
    }
    __syncthreads();
    #pragma unroll
    for (int it = 0; it < 2; ++it) {
        const int lin = (it << 11) + (tid << 3);
        const int nn = lin >> 6, kk = lin & 63;
        bf16x8 o;
        #pragma unroll
        for (int j = 0; j < 8; ++j) o[j] = Ls[kk + j][nn];
        *(bf16x8*)(dst + (size_t)(n0 + nn) * K + k0 + kk) = o;
    }
}

// ---------------- bf16 GEMM, B^T input, 2-phase dbuf pipeline, BK=32 ----------------
// A [M][K] bf16, Bt [N][K] bf16.
// MODE 0 (BN=128): scatter q/k packed [bh][t][d] + v transposed [bh][d][t] via LDS-pack
// MODE 1 (BN=64):  f32 out[M][N] + bias, direct stores
template <int MODE, int BN>
__global__ __launch_bounds__(256)
void gemm_bt(const bf16* __restrict__ A, const bf16* __restrict__ Bt,
             const float* __restrict__ bias,
             bf16* __restrict__ qw, bf16* __restrict__ kw, bf16* __restrict__ vw,
             float* __restrict__ outf, int M, int N, int K)
{
    constexpr int BK = 32;
    constexpr int MF = (BN == 128) ? 4 : 2;
    constexpr int NF = 4;
    constexpr int AE = 128 * BK;
    constexpr int BE = BN * BK;

    __shared__ __align__(16) bf16 smem[2 * AE + 2 * BE];
    bf16* const As0 = smem;
    bf16* const As1 = smem + AE;
    bf16* const Bs0 = smem + 2 * AE;
    bf16* const Bs1 = smem + 2 * AE + BE;

    const int tid  = threadIdx.x;
    const int lane = tid & 63;
    const int wid  = tid >> 6;
    const int l16  = lane & 15;
    const int g    = lane >> 4;
    const int wrb  = (BN == 128) ? ((wid >> 1) << 6) : (wid << 5);
    const int wcb  = (BN == 128) ? ((wid & 1) << 6) : 0;
    const int m0   = blockIdx.y << 7;
    const int n0   = blockIdx.x * BN;

    // staging: 16 rows x 64B per instr; source chunk XOR-preswizzled by (row>>1)&3
    const int srow = lane >> 2;
    const int schk = lane & 3;
    const int rA0 = (wid << 5) + srow;
    const int rA1 = rA0 + 16;
    const int rB0 = wid * (BN / 4) + srow;
    const int rB1 = rB0 + 16;
    const bf16* pa0 = A  + (size_t)(m0 + rA0) * K + ((schk ^ ((rA0 >> 1) & 3)) << 3);
    const bf16* pa1 = A  + (size_t)(m0 + rA1) * K + ((schk ^ ((rA1 >> 1) & 3)) << 3);
    const bf16* pb0 = Bt + (size_t)(n0 + rB0) * K + ((schk ^ ((rB0 >> 1) & 3)) << 3);
    const bf16* pb1 = Bt + (size_t)(n0 + rB1) * K + ((schk ^ ((rB1 >> 1) & 3)) << 3);
    const int dA0 = (wid << 5) * BK, dA1 = dA0 + 16 * BK;
    const int dB0 = (wid * (BN / 4)) * BK, dB1 = dB0 + 16 * BK;

    // fragment read offsets (elems), swizzle-matched
    int offA[MF], offB[NF];
    #pragma unroll
    for (int mf = 0; mf < MF; ++mf) {
        const int r = wrb + (mf << 4) + l16;
        offA[mf] = r * BK + ((g ^ ((r >> 1) & 3)) << 3);
    }
    #pragma unroll
    for (int nf = 0; nf < NF; ++nf) {
        const int r = wcb + (nf << 4) + l16;
        offB[nf] = r * BK + ((g ^ ((r >> 1) & 3)) << 3);
    }

    f32x4 acc[MF][NF];
    #pragma unroll
    for (int i = 0; i < MF; ++i)
        #pragma unroll
        for (int j = 0; j < NF; ++j) acc[i][j] = zero4();

    const int nk = K >> 5;
    // prologue: stage tile 0 into buf0
    gl_lds16(pa0, As0 + dA0); gl_lds16(pa1, As0 + dA1);
    gl_lds16(pb0, Bs0 + dB0);
    if (BN == 128) gl_lds16(pb1, Bs0 + dB1);
    pa0 += BK; pa1 += BK; pb0 += BK; pb1 += BK;
    __syncthreads();

    for (int kt = 0; kt < nk; ++kt) {
        const bool odd = kt & 1;
        if (kt + 1 < nk) {                       // prefetch next tile into other buffer
            bf16* an = odd ? As0 : As1;
            bf16* bn = odd ? Bs0 : Bs1;
            gl_lds16(pa0, an + dA0); gl_lds16(pa1, an + dA1);
            gl_lds16(pb0, bn + dB0);
            if (BN == 128) gl_lds16(pb1, bn + dB1);
            pa0 += BK; pa1 += BK; pb0 += BK; pb1 += BK;
        }
        const bf16* ac = odd ? As1 : As0;
        const bf16* bc = odd ? Bs1 : Bs0;
        bf16x8 af[MF], bfr[NF];
        #pragma unroll
        for (int mf = 0; mf < MF; ++mf) af[mf] = *(const bf16x8*)&ac[offA[mf]];
        #pragma unroll
        for (int nf = 0; nf < NF; ++nf) bfr[nf] = *(const bf16x8*)&bc[offB[nf]];
        #pragma unroll
        for (int mf = 0; mf < MF; ++mf)
            #pragma unroll
            for (int nf = 0; nf < NF; ++nf)
                acc[mf][nf] = MFMA16(af[mf], bfr[nf], acc[mf][nf]);
        __syncthreads();                         // drains vmcnt(0): prefetched tile ready
    }

    if (MODE == 0) {
        // ---- LDS-pack epilogue: 128x128 bf16 tile reusing smem (exactly 32KB) ----
        bf16* const Es = smem;
        const int bq  = m0 >> 10;
        const int tb  = m0 & 1023;               // time index within batch
        const int hh0 = (n0 & 1023) >> 6;
        const bool isV = (n0 >= 2048);
        if (isV) {
            #pragma unroll
            for (int mf = 0; mf < MF; ++mf)
                #pragma unroll
                for (int nf = 0; nf < NF; ++nf) {
                    const int nn = wcb + (nf << 4) + l16;
                    const float bs = bias[n0 + nn];
                    bf16x4 p;
                    #pragma unroll
                    for (int j = 0; j < 4; ++j) p[j] = (bf16)(acc[mf][nf][j] + bs);
                    *(bf16x4*)&Es[nn * 128 + wrb + (mf << 4) + (g << 2)] = p;  // transposed
                }
        } else {
            #pragma unroll
            for (int mf = 0; mf < MF; ++mf)
                #pragma unroll
                for (int nf = 0; nf < NF; ++nf) {
                    const int nn = wcb + (nf << 4) + l16;
                    const float bs = bias[n0 + nn];
                    #pragma unroll
                    for (int j = 0; j < 4; ++j) {
                        const int mm = wrb + (mf << 4) + (g << 2) + j;
                        Es[mm * 128 + nn] = (bf16)(acc[mf][nf][j] + bs);
                    }
                }
        }
        __syncthreads();
        #pragma unroll
        for (int it = 0; it < 8; ++it) {
            const int idx = (it << 8) + tid;
            const int row = idx >> 4, ch = idx & 15;
            const bf16x8 v = *(const bf16x8*)&Es[row * 128 + (ch << 3)];
            if (isV) {
                const int dd = row & 63, hh = hh0 + (row >> 6);
                *(bf16x8*)(vw + ((size_t)((bq << 4) + hh) << 16) + ((size_t)dd << 10)
                           + tb + (ch << 3)) = v;
            } else {
                const int t = tb + row;
                const int cc = ch << 3;
                const int hh = hh0 + (cc >> 6);
                bf16* const dst = (n0 < 1024) ? qw : kw;
                *(bf16x8*)(dst + ((size_t)((bq << 4) + hh) << 16) + ((size_t)t << 6)
                           + (cc & 63)) = v;
            }
        }
    } else {
        #pragma unroll
        for (int mf = 0; mf < MF; ++mf)
            #pragma unroll
            for (int nf = 0; nf < NF; ++nf) {
                const int ng = n0 + wcb + (nf << 4) + l16;
                const float bs = bias[ng];
                #pragma unroll
                for (int j = 0; j < 4; ++j) {
                    const int mg = m0 + wrb + (mf << 4) + (g << 2) + j;
                    outf[(size_t)mg * N + ng] = acc[mf][nf][j] + bs;
                }
            }
    }
}

// ---------------- flash attention: 4 waves x 16 q-rows, LDS K/V^T dbuf 2-phase ----------------
// Q,K [bh][1024][64]; Vt [bh][64][1024]; out att [4096][1024] bf16.
// grid (16, 64); block qb handles 64 q-rows [qb*64, qb*64+64).
// Softmax in exp2 domain (Q pre-scaled by 0.125*log2e); defer-max rescale (THR=8).
__global__ __launch_bounds__(256)
void attn_k(const bf16* __restrict__ Qp, const bf16* __restrict__ Kp,
            const bf16* __restrict__ Vt, bf16* __restrict__ att)
{
    __shared__ __align__(16) bf16 Kl0[64 * 64], Kl1[64 * 64];
    __shared__ __align__(16) bf16 Vl0[64 * 64], Vl1[64 * 64];
    __shared__ __align__(16) bf16 Ps[4][16 * 72];

    const int qb = blockIdx.x;          // 0..15
    const int bh = blockIdx.y;          // 0..63
    const int b  = bh >> 4, h = bh & 15;

    const int tid  = threadIdx.x;
    const int lane = tid & 63;
    const int wid  = tid >> 6;
    const int g    = lane >> 4;
    const int l16  = lane & 15;
    const int g8   = g << 3;

    const size_t hb = (size_t)bh << 16;
    const bf16* Qh = Qp + hb;
    const bf16* Kh = Kp + hb;
    const bf16* Vh = Vt + hb;

    // staging: 8 rows x 128B per instr; source chunk XOR-preswizzled by row&7
    const int srow = lane >> 3;                    // 0..7
    const int sswz = ((lane & 7) ^ srow) << 3;     // elems
    const int kr0  = (wid << 4) + srow;
    const int kr1  = kr0 + 8;
    const int dst0 = (wid << 4) << 6;
    const int dst1 = ((wid << 4) + 8) << 6;

    // fragment read offsets (elems), swizzle-matched; shared by K and V^T tiles
    int offKV[2][4];
    #pragma unroll
    for (int ks = 0; ks < 2; ++ks)
        #pragma unroll
        for (int cb = 0; cb < 4; ++cb) {
            const int r = (cb << 4) + l16;
            offKV[ks][cb] = (r << 6) + (((((ks << 2) + g)) ^ (r & 7)) << 3);
        }

    bf16* const Pw = &Ps[wid][0];
    const int q0 = qb << 6;

    // hoist Q fragments for this wave's 16 rows, pre-scaled by 0.125*log2(e)
    const float QSCALE = 0.125f * 1.44269504f;
    const bf16* qp = Qh + ((size_t)(q0 + (wid << 4) + l16) << 6) + g8;
    bf16x8 qf0 = *(const bf16x8*)qp;
    bf16x8 qf1 = *(const bf16x8*)(qp + 32);
    #pragma unroll
    for (int e = 0; e < 8; ++e) {
        qf0[e] = (bf16)(QSCALE * (float)qf0[e]);
        qf1[e] = (bf16)(QSCALE * (float)qf1[e]);
    }

    f32x4 acc_o[4];
    float m_r[4], l_r[4];
    #pragma unroll
    for (int i = 0; i < 4; ++i) { acc_o[i] = zero4(); m_r[i] = -1e30f; l_r[i] = 0.f; }

    // prologue: stage kv tile 0 into buf0
    gl_lds16(Kh + ((size_t)kr0 << 6) + sswz, Kl0 + dst0);
    gl_lds16(Kh + ((size_t)kr1 << 6) + sswz, Kl0 + dst1);
    gl_lds16(Vh + ((size_t)kr0 << 10) + sswz, Vl0 + dst0);
    gl_lds16(Vh + ((size_t)kr1 << 10) + sswz, Vl0 + dst1);
    __syncthreads();

    for (int kt = 0; kt <= qb; ++kt) {
        const bool odd = kt & 1;
        if (kt < qb) {                       // prefetch next kv tile
            const int kv1 = (kt + 1) << 6;
            bf16* Kn = odd ? Kl0 : Kl1;
            bf16* Vn = odd ? Vl0 : Vl1;
            gl_lds16(Kh + ((size_t)(kv1 + kr0) << 6) + sswz, Kn + dst0);
            gl_lds16(Kh + ((size_t)(kv1 + kr1) << 6) + sswz, Kn + dst1);
            gl_lds16(Vh + ((size_t)kr0 << 10) + kv1 + sswz, Vn + dst0);
            gl_lds16(Vh + ((size_t)kr1 << 10) + kv1 + sswz, Vn + dst1);
        }
        const bf16* Kc = odd ? Kl1 : Kl0;
        const bf16* Vc = odd ? Vl1 : Vl0;

        // ---- S~ = (Q*0.125*log2e) K^T (log2-domain logits) ----
        f32x4 sacc[4];
        #pragma unroll
        for (int cb = 0; cb < 4; ++cb) sacc[cb] = zero4();
        #pragma unroll
        for (int cb = 0; cb < 4; ++cb) {
            const bf16x8 kf = *(const bf16x8*)&Kc[offKV[0][cb]];
            sacc[cb] = MFMA16(qf0, kf, sacc[cb]);
        }
        #pragma unroll
        for (int cb = 0; cb < 4; ++cb) {
            const bf16x8 kf = *(const bf16x8*)&Kc[offKV[1][cb]];
            sacc[cb] = MFMA16(qf1, kf, sacc[cb]);
        }
        // ---- causal mask on diagonal tile ----
        if (kt == qb) {
            #pragma unroll
            for (int cb = 0; cb < 4; ++cb) {
                const int col = (cb << 4) + l16;
                #pragma unroll
                for (int j = 0; j < 4; ++j) {
                    const int row = (wid << 4) + (g << 2) + j;
                    if (col > row) sacc[cb][j] = -1e30f;
                }
            }
        }
        // ---- online softmax, exp2 domain, defer-max (THR=8 -> P <= 256) ----
        float pmax[4];
        #pragma unroll
        for (int j = 0; j < 4; ++j) {
            float v = fmaxf(fmaxf(sacc[0][j], sacc[1][j]), fmaxf(sacc[2][j], sacc[3][j]));
            v = fmaxf(v, __shfl_xor(v, 1));
            v = fmaxf(v, __shfl_xor(v, 2));
            v = fmaxf(v, __shfl_xor(v, 4));
            v = fmaxf(v, __shfl_xor(v, 8));
            pmax[j] = v;
        }
        bool grow = false;
        #pragma unroll
        for (int j = 0; j < 4; ++j) grow = grow || (pmax[j] > m_r[j] + 8.f);
        if (__any((int)grow)) {
            #pragma unroll
            for (int j = 0; j < 4; ++j) {
                const float mn = fmaxf(m_r[j], pmax[j]);
                const float sc = __builtin_amdgcn_exp2f(m_r[j] - mn);
                m_r[j] = mn;
                l_r[j] *= sc;
                acc_o[0][j] *= sc;
                acc_o[1][j] *= sc;
                acc_o[2][j] *= sc;
                acc_o[3][j] *= sc;
            }
        }
        float rsum[4];
        #pragma unroll
        for (int j = 0; j < 4; ++j) rsum[j] = 0.f;
        #pragma unroll
        for (int cb = 0; cb < 4; ++cb)
            #pragma unroll
            for (int j = 0; j < 4; ++j) {
                const float p = __builtin_amdgcn_exp2f(sacc[cb][j] - m_r[j]);
                sacc[cb][j] = p;
                rsum[j] += p;
            }
        #pragma unroll
        for (int j = 0; j < 4; ++j) {
            float v = rsum[j];
            v += __shfl_xor(v, 1);
            v += __shfl_xor(v, 2);
            v += __shfl_xor(v, 4);
            v += __shfl_xor(v, 8);
            l_r[j] += v;
        }
        // ---- P relayout via per-wave LDS ----
        #pragma unroll
        for (int cb = 0; cb < 4; ++cb)
            #pragma unroll
            for (int j = 0; j < 4; ++j)
                Pw[((g << 2) + j) * 72 + (cb << 4) + l16] = (bf16)sacc[cb][j];
        // ---- O += P V ----
        #pragma unroll
        for (int ks = 0; ks < 2; ++ks) {
            const bf16x8 pf = *(const bf16x8*)&Pw[l16 * 72 + (ks << 5) + g8];
            #pragma unroll
            for (int cb = 0; cb < 4; ++cb) {
                const bf16x8 vf = *(const bf16x8*)&Vc[offKV[ks][cb]];
                acc_o[cb] = MFMA16(pf, vf, acc_o[cb]);
            }
        }
        __syncthreads();
    }

    // ---- epilogue: att[b*1024+t][h*64+d] ----
    float inv_l[4];
    #pragma unroll
    for (int j = 0; j < 4; ++j) inv_l[j] = 1.f / l_r[j];
    #pragma unroll
    for (int cb = 0; cb < 4; ++cb)
        #pragma unroll
        for (int j = 0; j < 4; ++j) {
            const int t = q0 + (wid << 4) + (g << 2) + j;
            const int d = (cb << 4) + l16;
            att[(((size_t)b << 10) + t) * 1024 + (h << 6) + d]
                = (bf16)(acc_o[cb][j] * inv_l[j]);
        }
}

extern "C" void kernel_launch(void* const* d_in, const int* in_sizes, int n_in,
                              void* d_out, int out_size, void* d_ws, size_t ws_size,
                              hipStream_t stream)
{
    const float* x      = (const float*)d_in[0];
    const float* w_attn = (const float*)d_in[1];
    const float* b_attn = (const float*)d_in[2];
    const float* w_proj = (const float*)d_in[3];
    const float* b_proj = (const float*)d_in[4];
    float* out = (float*)d_out;

    // workspace layout (bf16 elems)
    bf16* xb  = (bf16*)d_ws;                        // [4096][1024]
    bf16* wT  = xb  + (size_t)4096 * 1024;          // [3072][1024]
    bf16* wpT = wT  + (size_t)3072 * 1024;          // [1024][1024]
    bf16* qw  = wpT + (size_t)1024 * 1024;          // [64 bh][1024 t][64 d]
    bf16* kw  = qw  + (size_t)64 * 1024 * 64;       // [64 bh][1024 t][64 d]
    bf16* vw  = kw  + (size_t)64 * 1024 * 64;       // [64 bh][64 d][1024 t]
    bf16* aw  = vw  + (size_t)64 * 1024 * 64;       // [4096][1024]

    conv_k<<<2048, 256, 0, stream>>>(x, xb, 4096 * 1024);
    transp_k<<<dim3(48, 16), 256, 0, stream>>>(w_attn, wT, 1024, 3072);
    transp_k<<<dim3(16, 16), 256, 0, stream>>>(w_proj, wpT, 1024, 1024);

    gemm_bt<0, 128><<<dim3(24, 32), 256, 0, stream>>>(xb, wT, b_attn, qw, kw, vw,
                                                      nullptr, 4096, 3072, 1024);
    attn_k<<<dim3(16, 64), 256, 0, stream>>>(qw, kw, vw, aw);
    gemm_bt<1, 64><<<dim3(16, 32), 256, 0, stream>>>(aw, wpT, b_proj, nullptr, nullptr, nullptr,
                                                     out, 4096, 1024, 1024);
}

// Round 7
// 98.789 us; speedup vs baseline: 1.3429x; 1.3429x over previous
//
#include <hip/hip_runtime.h>

typedef __bf16 bf16;
typedef float f32x4 __attribute__((ext_vector_type(4)));
typedef bf16 bf16x4 __attribute__((ext_vector_type(4)));
typedef bf16 bf16x8 __attribute__((ext_vector_type(8)));

#define MFMA16(a, b, c) __builtin_amdgcn_mfma_f32_16x16x32_bf16((a), (b), (c), 0, 0, 0)

__device__ __forceinline__ f32x4 zero4() {
    f32x4 z; z[0] = 0.f; z[1] = 0.f; z[2] = 0.f; z[3] = 0.f; return z;
}
// async global -> LDS, 16B/lane. LDS dest = wave-uniform base + lane*16.
__device__ __forceinline__ void gl_lds16(const bf16* g, bf16* l) {
    __builtin_amdgcn_global_load_lds(
        (const __attribute__((address_space(1))) void*)g,
        (__attribute__((address_space(3))) void*)l, 16, 0, 0);
}

// ---------------- prep: f32 -> bf16 elementwise ----------------
__global__ __launch_bounds__(256) void conv_k(const float* __restrict__ src,
                                              bf16* __restrict__ dst, int n)
{
    const int i = (blockIdx.x * 256 + threadIdx.x) * 8;
    if (i >= n) return;
    const float4 a = *(const float4*)(src + i);
    const float4 b = *(const float4*)(src + i + 4);
    bf16x8 o;
    o[0] = (bf16)a.x; o[1] = (bf16)a.y; o[2] = (bf16)a.z; o[3] = (bf16)a.w;
    o[4] = (bf16)b.x; o[5] = (bf16)b.y; o[6] = (bf16)b.z; o[7] = (bf16)b.w;
    *(bf16x8*)(dst + i) = o;
}

// ---------------- prep: transpose+convert w [K][N] f32 -> wT [N][K] bf16 ----------------
__global__ __launch_bounds__(256) void transp_k(const float* __restrict__ src,
                                                bf16* __restrict__ dst, int K, int N)
{
    __shared__ bf16 Ls[64][72];
    const int tid = threadIdx.x;
    const int k0 = blockIdx.y << 6;
    const int n0 = blockIdx.x << 6;
    #pragma unroll
    for (int it = 0; it < 4; ++it) {
        const int lin = (it << 10) + (tid << 2);
        const int r = lin >> 6, c = lin & 63;
        const float4 v = *(const float4*)(src + (size_t)(k0 + r) * N + n0 + c);
        bf16x4 o; o[0] = (bf16)v.x; o[1] = (bf16)v.y; o[2] = (bf16)v.z; o[3] = (bf16)v.w;
        *(bf16x4*)&Ls[r][c] = o;
    }
    __syncthreads();
    #pragma unroll
    for (int it = 0; it < 2; ++it) {
        const int lin = (it << 11) + (tid << 3);
        const int nn = lin >> 6, kk = lin & 63;
        bf16x8 o;
        #pragma unroll
        for (int j = 0; j < 8; ++j) o[j] = Ls[kk + j][nn];
        *(bf16x8*)(dst + (size_t)(n0 + nn) * K + k0 + kk) = o;
    }
}

// ---------------- bf16 GEMM, B^T input, 2-phase dbuf pipeline, BK=32 ----------------
// A [M][K] bf16, Bt [N][K] bf16.
// MODE 0 (BN=128): scatter q/k packed [bh][t][d] + v transposed [bh][d][t'] via LDS-pack,
//                  where t' permutes t within 32-blocks (p = 32s+8g+4h+j <-> t = 32s+16h+4g+j)
//                  so attention PV fragments are contiguous b128 reads.
// MODE 1 (BN=64):  f32 out[M][N] + bias, direct stores
template <int MODE, int BN>
__global__ __launch_bounds__(256)
void gemm_bt(const bf16* __restrict__ A, const bf16* __restrict__ Bt,
             const float* __restrict__ bias,
             bf16* __restrict__ qw, bf16* __restrict__ kw, bf16* __restrict__ vw,
             float* __restrict__ outf, int M, int N, int K)
{
    constexpr int BK = 32;
    constexpr int MF = (BN == 128) ? 4 : 2;
    constexpr int NF = 4;
    constexpr int AE = 128 * BK;
    constexpr int BE = BN * BK;

    __shared__ __align__(16) bf16 smem[2 * AE + 2 * BE];
    bf16* const As0 = smem;
    bf16* const As1 = smem + AE;
    bf16* const Bs0 = smem + 2 * AE;
    bf16* const Bs1 = smem + 2 * AE + BE;

    const int tid  = threadIdx.x;
    const int lane = tid & 63;
    const int wid  = tid >> 6;
    const int l16  = lane & 15;
    const int g    = lane >> 4;
    const int wrb  = (BN == 128) ? ((wid >> 1) << 6) : (wid << 5);
    const int wcb  = (BN == 128) ? ((wid & 1) << 6) : 0;
    const int m0   = blockIdx.y << 7;
    const int n0   = blockIdx.x * BN;

    // staging: 16 rows x 64B per instr; source chunk XOR-preswizzled by (row>>1)&3
    const int srow = lane >> 2;
    const int schk = lane & 3;
    const int rA0 = (wid << 5) + srow;
    const int rA1 = rA0 + 16;
    const int rB0 = wid * (BN / 4) + srow;
    const int rB1 = rB0 + 16;
    const bf16* pa0 = A  + (size_t)(m0 + rA0) * K + ((schk ^ ((rA0 >> 1) & 3)) << 3);
    const bf16* pa1 = A  + (size_t)(m0 + rA1) * K + ((schk ^ ((rA1 >> 1) & 3)) << 3);
    const bf16* pb0 = Bt + (size_t)(n0 + rB0) * K + ((schk ^ ((rB0 >> 1) & 3)) << 3);
    const bf16* pb1 = Bt + (size_t)(n0 + rB1) * K + ((schk ^ ((rB1 >> 1) & 3)) << 3);
    const int dA0 = (wid << 5) * BK, dA1 = dA0 + 16 * BK;
    const int dB0 = (wid * (BN / 4)) * BK, dB1 = dB0 + 16 * BK;

    // fragment read offsets (elems), swizzle-matched
    int offA[MF], offB[NF];
    #pragma unroll
    for (int mf = 0; mf < MF; ++mf) {
        const int r = wrb + (mf << 4) + l16;
        offA[mf] = r * BK + ((g ^ ((r >> 1) & 3)) << 3);
    }
    #pragma unroll
    for (int nf = 0; nf < NF; ++nf) {
        const int r = wcb + (nf << 4) + l16;
        offB[nf] = r * BK + ((g ^ ((r >> 1) & 3)) << 3);
    }

    f32x4 acc[MF][NF];
    #pragma unroll
    for (int i = 0; i < MF; ++i)
        #pragma unroll
        for (int j = 0; j < NF; ++j) acc[i][j] = zero4();

    const int nk = K >> 5;
    // prologue: stage tile 0 into buf0
    gl_lds16(pa0, As0 + dA0); gl_lds16(pa1, As0 + dA1);
    gl_lds16(pb0, Bs0 + dB0);
    if (BN == 128) gl_lds16(pb1, Bs0 + dB1);
    pa0 += BK; pa1 += BK; pb0 += BK; pb1 += BK;
    __syncthreads();

    for (int kt = 0; kt < nk; ++kt) {
        const bool odd = kt & 1;
        if (kt + 1 < nk) {                       // prefetch next tile into other buffer
            bf16* an = odd ? As0 : As1;
            bf16* bn = odd ? Bs0 : Bs1;
            gl_lds16(pa0, an + dA0); gl_lds16(pa1, an + dA1);
            gl_lds16(pb0, bn + dB0);
            if (BN == 128) gl_lds16(pb1, bn + dB1);
            pa0 += BK; pa1 += BK; pb0 += BK; pb1 += BK;
        }
        const bf16* ac = odd ? As1 : As0;
        const bf16* bc = odd ? Bs1 : Bs0;
        bf16x8 af[MF], bfr[NF];
        #pragma unroll
        for (int mf = 0; mf < MF; ++mf) af[mf] = *(const bf16x8*)&ac[offA[mf]];
        #pragma unroll
        for (int nf = 0; nf < NF; ++nf) bfr[nf] = *(const bf16x8*)&bc[offB[nf]];
        #pragma unroll
        for (int mf = 0; mf < MF; ++mf)
            #pragma unroll
            for (int nf = 0; nf < NF; ++nf)
                acc[mf][nf] = MFMA16(af[mf], bfr[nf], acc[mf][nf]);
        __syncthreads();                         // drains vmcnt(0): prefetched tile ready
    }

    if (MODE == 0) {
        // ---- LDS-pack epilogue: 128x128 bf16 tile reusing smem (exactly 32KB) ----
        bf16* const Es = smem;
        const int bq  = m0 >> 10;
        const int tb  = m0 & 1023;               // time index within batch
        const int hh0 = (n0 & 1023) >> 6;
        const bool isV = (n0 >= 2048);
        if (isV) {
            #pragma unroll
            for (int mf = 0; mf < MF; ++mf)
                #pragma unroll
                for (int nf = 0; nf < NF; ++nf) {
                    const int nn = wcb + (nf << 4) + l16;
                    const float bs = bias[n0 + nn];
                    bf16x4 p;
                    #pragma unroll
                    for (int j = 0; j < 4; ++j) p[j] = (bf16)(acc[mf][nf][j] + bs);
                    // transposed + PV-kmap permuted: t = 32s+16h+4g'+j -> pos 32s+8g'+4h+j
                    const int m = wrb + (mf << 4) + (g << 2);
                    const int pp = ((m >> 5) << 5) + (((m >> 2) & 3) << 3) + (((m >> 4) & 1) << 2);
                    *(bf16x4*)&Es[nn * 128 + pp] = p;
                }
        } else {
            #pragma unroll
            for (int mf = 0; mf < MF; ++mf)
                #pragma unroll
                for (int nf = 0; nf < NF; ++nf) {
                    const int nn = wcb + (nf << 4) + l16;
                    const float bs = bias[n0 + nn];
                    #pragma unroll
                    for (int j = 0; j < 4; ++j) {
                        const int mm = wrb + (mf << 4) + (g << 2) + j;
                        Es[mm * 128 + nn] = (bf16)(acc[mf][nf][j] + bs);
                    }
                }
        }
        __syncthreads();
        #pragma unroll
        for (int it = 0; it < 8; ++it) {
            const int idx = (it << 8) + tid;
            const int row = idx >> 4, ch = idx & 15;
            const bf16x8 v = *(const bf16x8*)&Es[row * 128 + (ch << 3)];
            if (isV) {
                const int dd = row & 63, hh = hh0 + (row >> 6);
                *(bf16x8*)(vw + ((size_t)((bq << 4) + hh) << 16) + ((size_t)dd << 10)
                           + tb + (ch << 3)) = v;
            } else {
                const int t = tb + row;
                const int cc = ch << 3;
                const int hh = hh0 + (cc >> 6);
                bf16* const dst = (n0 < 1024) ? qw : kw;
                *(bf16x8*)(dst + ((size_t)((bq << 4) + hh) << 16) + ((size_t)t << 6)
                           + (cc & 63)) = v;
            }
        }
    } else {
        #pragma unroll
        for (int mf = 0; mf < MF; ++mf)
            #pragma unroll
            for (int nf = 0; nf < NF; ++nf) {
                const int ng = n0 + wcb + (nf << 4) + l16;
                const float bs = bias[ng];
                #pragma unroll
                for (int j = 0; j < 4; ++j) {
                    const int mg = m0 + wrb + (mf << 4) + (g << 2) + j;
                    outf[(size_t)mg * N + ng] = acc[mf][nf][j] + bs;
                }
            }
    }
}

// ---------------- flash attention: swapped-QK^T, in-register softmax ----------------
// Q,K [bh][1024][64]; Vt [bh][64][1024 t-permuted]; out att [4096][1024] bf16.
// grid (8, 64); block bx does q-blocks {bx, 15-bx} of 64 rows -> 17 kv-tiles/block uniform.
// S^T = mfma(K,Q): lane owns q-col = l16, kv-rows = 16cb+4g+j -> scalar m/l stats,
// 2 shuffles per reduce, P^T stays in registers, O^T = mfma(V^T, P^T).
__global__ __launch_bounds__(256)
void attn_k(const bf16* __restrict__ Qp, const bf16* __restrict__ Kp,
            const bf16* __restrict__ Vt, bf16* __restrict__ att)
{
    __shared__ __align__(16) bf16 Kl0[64 * 64], Kl1[64 * 64];
    __shared__ __align__(16) bf16 Vl0[64 * 64], Vl1[64 * 64];

    const int bx = blockIdx.x;          // 0..7
    const int bh = blockIdx.y;          // 0..63
    const int b  = bh >> 4, h = bh & 15;

    const int tid  = threadIdx.x;
    const int lane = tid & 63;
    const int wid  = tid >> 6;
    const int g    = lane >> 4;
    const int l16  = lane & 15;
    const int g8   = g << 3;

    const size_t hb = (size_t)bh << 16;
    const bf16* Qh = Qp + hb;
    const bf16* Kh = Kp + hb;
    const bf16* Vh = Vt + hb;

    // staging: 8 rows x 128B per instr; source chunk XOR-preswizzled by row&7
    const int srow = lane >> 3;                    // 0..7
    const int sswz = ((lane & 7) ^ srow) << 3;     // elems
    const int kr0  = (wid << 4) + srow;
    const int kr1  = kr0 + 8;
    const int dst0 = (wid << 4) << 6;
    const int dst1 = ((wid << 4) + 8) << 6;

    // fragment read offsets (elems), swizzle-matched; rows = kv (K) or d (V^T)
    int offKV[2][4];
    #pragma unroll
    for (int ks = 0; ks < 2; ++ks)
        #pragma unroll
        for (int cb = 0; cb < 4; ++cb) {
            const int r = (cb << 4) + l16;
            offKV[ks][cb] = (r << 6) + (((((ks << 2) + g)) ^ (r & 7)) << 3);
        }

    const float QSCALE = 0.125f * 1.44269504f;     // fold 1/sqrt(d) * log2(e)

    for (int pass = 0; pass < 2; ++pass) {
        const int qb = pass ? (15 - bx) : bx;
        const int q0 = qb << 6;

        // hoist Q as B-fragment (col q = l16), pre-scaled
        const bf16* qp = Qh + ((size_t)(q0 + (wid << 4) + l16) << 6) + g8;
        bf16x8 qf0 = *(const bf16x8*)qp;
        bf16x8 qf1 = *(const bf16x8*)(qp + 32);
        #pragma unroll
        for (int e = 0; e < 8; ++e) {
            qf0[e] = (bf16)(QSCALE * (float)qf0[e]);
            qf1[e] = (bf16)(QSCALE * (float)qf1[e]);
        }

        f32x4 acc_o[4];                 // O^T: row d = 16db+4g+j, col q = l16
        float m_r = -1e30f, l_r = 0.f;  // per-lane scalar stats (one q per lane)
        #pragma unroll
        for (int i = 0; i < 4; ++i) acc_o[i] = zero4();

        // prologue: stage kv tile 0 into buf0
        gl_lds16(Kh + ((size_t)kr0 << 6) + sswz, Kl0 + dst0);
        gl_lds16(Kh + ((size_t)kr1 << 6) + sswz, Kl0 + dst1);
        gl_lds16(Vh + ((size_t)kr0 << 10) + sswz, Vl0 + dst0);
        gl_lds16(Vh + ((size_t)kr1 << 10) + sswz, Vl0 + dst1);
        __syncthreads();

        for (int kt = 0; kt <= qb; ++kt) {
            const bool odd = kt & 1;
            if (kt < qb) {                       // prefetch next kv tile
                const int kv1 = (kt + 1) << 6;
                bf16* Kn = odd ? Kl0 : Kl1;
                bf16* Vn = odd ? Vl0 : Vl1;
                gl_lds16(Kh + ((size_t)(kv1 + kr0) << 6) + sswz, Kn + dst0);
                gl_lds16(Kh + ((size_t)(kv1 + kr1) << 6) + sswz, Kn + dst1);
                gl_lds16(Vh + ((size_t)kr0 << 10) + kv1 + sswz, Vn + dst0);
                gl_lds16(Vh + ((size_t)kr1 << 10) + kv1 + sswz, Vn + dst1);
            }
            const bf16* Kc = odd ? Kl1 : Kl0;
            const bf16* Vc = odd ? Vl1 : Vl0;

            // ---- S^T = mfma(K, Q): sacc[cb][j] = S~[kv=16cb+4g+j][q=l16] ----
            f32x4 sacc[4];
            #pragma unroll
            for (int cb = 0; cb < 4; ++cb) sacc[cb] = zero4();
            #pragma unroll
            for (int cb = 0; cb < 4; ++cb) {
                const bf16x8 kf = *(const bf16x8*)&Kc[offKV[0][cb]];
                sacc[cb] = MFMA16(kf, qf0, sacc[cb]);
            }
            #pragma unroll
            for (int cb = 0; cb < 4; ++cb) {
                const bf16x8 kf = *(const bf16x8*)&Kc[offKV[1][cb]];
                sacc[cb] = MFMA16(kf, qf1, sacc[cb]);
            }
            // ---- causal mask on diagonal tile ----
            if (kt == qb) {
                const int qloc = (wid << 4) + l16;
                #pragma unroll
                for (int cb = 0; cb < 4; ++cb) {
                    #pragma unroll
                    for (int j = 0; j < 4; ++j) {
                        const int kvloc = (cb << 4) + (g << 2) + j;
                        if (kvloc > qloc) sacc[cb][j] = -1e30f;
                    }
                }
            }
            // ---- online softmax, exp2 domain, per-lane scalar, defer-max THR=8 ----
            float pm = sacc[0][0];
            #pragma unroll
            for (int cb = 0; cb < 4; ++cb)
                #pragma unroll
                for (int j = 0; j < 4; ++j) pm = fmaxf(pm, sacc[cb][j]);
            pm = fmaxf(pm, __shfl_xor(pm, 16));
            pm = fmaxf(pm, __shfl_xor(pm, 32));
            if (__any(pm > m_r + 8.f)) {
                const float mn = fmaxf(m_r, pm);
                const float sc = __builtin_amdgcn_exp2f(m_r - mn);
                m_r = mn;
                l_r *= sc;
                #pragma unroll
                for (int db = 0; db < 4; ++db)
                    #pragma unroll
                    for (int j = 0; j < 4; ++j) acc_o[db][j] *= sc;
            }
            float rsum = 0.f;
            #pragma unroll
            for (int cb = 0; cb < 4; ++cb)
                #pragma unroll
                for (int j = 0; j < 4; ++j) {
                    const float p = __builtin_amdgcn_exp2f(sacc[cb][j] - m_r);
                    sacc[cb][j] = p;
                    rsum += p;
                }
            rsum += __shfl_xor(rsum, 16);
            rsum += __shfl_xor(rsum, 32);
            l_r += rsum;
            // ---- P^T fragments in-register (k-map: kv = 32ks+16h+4g+j at elem i=4h+j) ----
            bf16x8 pf0, pf1;
            #pragma unroll
            for (int i = 0; i < 8; ++i) {
                pf0[i] = (bf16)sacc[i >> 2][i & 3];
                pf1[i] = (bf16)sacc[2 + (i >> 2)][i & 3];
            }
            // ---- O^T += V^T P^T (V stored t-permuted to match the k-map) ----
            #pragma unroll
            for (int db = 0; db < 4; ++db) {
                const bf16x8 vf = *(const bf16x8*)&Vc[offKV[0][db]];
                acc_o[db] = MFMA16(vf, pf0, acc_o[db]);
            }
            #pragma unroll
            for (int db = 0; db < 4; ++db) {
                const bf16x8 vf = *(const bf16x8*)&Vc[offKV[1][db]];
                acc_o[db] = MFMA16(vf, pf1, acc_o[db]);
            }
            __syncthreads();
        }

        // ---- epilogue: lane owns q-col l16 -> t fixed; d = 16db+4g+j ----
        const float inv_l = 1.f / l_r;
        const int t = q0 + (wid << 4) + l16;
        #pragma unroll
        for (int db = 0; db < 4; ++db) {
            bf16x4 o;
            #pragma unroll
            for (int j = 0; j < 4; ++j) o[j] = (bf16)(acc_o[db][j] * inv_l);
            *(bf16x4*)(att + (((size_t)b << 10) + t) * 1024 + (h << 6) + (db << 4) + (g << 2)) = o;
        }
        __syncthreads();   // all waves done before pass-2 prologue overwrites buf0
    }
}

extern "C" void kernel_launch(void* const* d_in, const int* in_sizes, int n_in,
                              void* d_out, int out_size, void* d_ws, size_t ws_size,
                              hipStream_t stream)
{
    const float* x      = (const float*)d_in[0];
    const float* w_attn = (const float*)d_in[1];
    const float* b_attn = (const float*)d_in[2];
    const float* w_proj = (const float*)d_in[3];
    const float* b_proj = (const float*)d_in[4];
    float* out = (float*)d_out;

    // workspace layout (bf16 elems)
    bf16* xb  = (bf16*)d_ws;                        // [4096][1024]
    bf16* wT  = xb  + (size_t)4096 * 1024;          // [3072][1024]
    bf16* wpT = wT  + (size_t)3072 * 1024;          // [1024][1024]
    bf16* qw  = wpT + (size_t)1024 * 1024;          // [64 bh][1024 t][64 d]
    bf16* kw  = qw  + (size_t)64 * 1024 * 64;       // [64 bh][1024 t][64 d]
    bf16* vw  = kw  + (size_t)64 * 1024 * 64;       // [64 bh][64 d][1024 t']
    bf16* aw  = vw  + (size_t)64 * 1024 * 64;       // [4096][1024]

    conv_k<<<2048, 256, 0, stream>>>(x, xb, 4096 * 1024);
    transp_k<<<dim3(48, 16), 256, 0, stream>>>(w_attn, wT, 1024, 3072);
    transp_k<<<dim3(16, 16), 256, 0, stream>>>(w_proj, wpT, 1024, 1024);

    gemm_bt<0, 128><<<dim3(24, 32), 256, 0, stream>>>(xb, wT, b_attn, qw, kw, vw,
                                                      nullptr, 4096, 3072, 1024);
    attn_k<<<dim3(8, 64), 256, 0, stream>>>(qw, kw, vw, aw);
    gemm_bt<1, 64><<<dim3(16, 32), 256, 0, stream>>>(aw, wpT, b_proj, nullptr, nullptr, nullptr,
                                                     out, 4096, 1024, 1024);
}

// Round 8
// 94.006 us; speedup vs baseline: 1.4112x; 1.0509x over previous
//
#include <hip/hip_runtime.h>

typedef __bf16 bf16;
typedef float f32x4 __attribute__((ext_vector_type(4)));
typedef bf16 bf16x4 __attribute__((ext_vector_type(4)));
typedef bf16 bf16x8 __attribute__((ext_vector_type(8)));

#define MFMA16(a, b, c) __builtin_amdgcn_mfma_f32_16x16x32_bf16((a), (b), (c), 0, 0, 0)

__device__ __forceinline__ f32x4 zero4() {
    f32x4 z; z[0] = 0.f; z[1] = 0.f; z[2] = 0.f; z[3] = 0.f; return z;
}
// async global -> LDS, 16B/lane. LDS dest = wave-uniform base + lane*16.
__device__ __forceinline__ void gl_lds16(const bf16* g, bf16* l) {
    __builtin_amdgcn_global_load_lds(
        (const __attribute__((address_space(1))) void*)g,
        (__attribute__((address_space(3))) void*)l, 16, 0, 0);
}

// ---------------- prep: f32 -> bf16 elementwise ----------------
__global__ __launch_bounds__(256) void conv_k(const float* __restrict__ src,
                                              bf16* __restrict__ dst, int n)
{
    const int i = (blockIdx.x * 256 + threadIdx.x) * 8;
    if (i >= n) return;
    const float4 a = *(const float4*)(src + i);
    const float4 b = *(const float4*)(src + i + 4);
    bf16x8 o;
    o[0] = (bf16)a.x; o[1] = (bf16)a.y; o[2] = (bf16)a.z; o[3] = (bf16)a.w;
    o[4] = (bf16)b.x; o[5] = (bf16)b.y; o[6] = (bf16)b.z; o[7] = (bf16)b.w;
    *(bf16x8*)(dst + i) = o;
}

// ---------------- prep: transpose+convert w [K][N] f32 -> wT [N][K] bf16 ----------------
__global__ __launch_bounds__(256) void transp_k(const float* __restrict__ src,
                                                bf16* __restrict__ dst, int K, int N)
{
    __shared__ bf16 Ls[64][72];
    const int tid = threadIdx.x;
    const int k0 = blockIdx.y << 6;
    const int n0 = blockIdx.x << 6;
    #pragma unroll
    for (int it = 0; it < 4; ++it) {
        const int lin = (it << 10) + (tid << 2);
        const int r = lin >> 6, c = lin & 63;
        const float4 v = *(const float4*)(src + (size_t)(k0 + r) * N + n0 + c);
        bf16x4 o; o[0] = (bf16)v.x; o[1] = (bf16)v.y; o[2] = (bf16)v.z; o[3] = (bf16)v.w;
        *(bf16x4*)&Ls[r][c] = o;
    }
    __syncthreads();
    #pragma unroll
    for (int it = 0; it < 2; ++it) {
        const int lin = (it << 11) + (tid << 3);
        const int nn = lin >> 6, kk = lin & 63;
        bf16x8 o;
        #pragma unroll
        for (int j = 0; j < 8; ++j) o[j] = Ls[kk + j][nn];
        *(bf16x8*)(dst + (size_t)(n0 + nn) * K + k0 + kk) = o;
    }
}

// ---------------- bf16 GEMM, B^T input, depth-2 counted-vmcnt pipeline, BK=32 ----------------
// Triple-buffered LDS; s_waitcnt vmcnt(LPI) keeps next tile's loads in flight across barriers.
// MODE 0 (BN=128): scatter q/k packed [bh][t][d] + v transposed+t-permuted [bh][d][t'] via LDS-pack
// MODE 1 (BN=64):  f32 out[M][N] + bias, direct stores
template <int MODE, int BN>
__global__ __launch_bounds__(256)
void gemm_bt(const bf16* __restrict__ A, const bf16* __restrict__ Bt,
             const float* __restrict__ bias,
             bf16* __restrict__ qw, bf16* __restrict__ kw, bf16* __restrict__ vw,
             float* __restrict__ outf, int M, int N, int K)
{
    constexpr int BK = 32;
    constexpr int MF = (BN == 128) ? 4 : 2;
    constexpr int NF = 4;
    constexpr int AE = 128 * BK;
    constexpr int BE = BN * BK;
    constexpr int LPI = (BN == 128) ? 4 : 3;     // gl_lds issues per wave per K-step

    __shared__ __align__(16) bf16 smem[3 * (AE + BE)];
    bf16* const Asb = smem;                      // 3 x AE
    bf16* const Bsb = smem + 3 * AE;             // 3 x BE

    const int tid  = threadIdx.x;
    const int lane = tid & 63;
    const int wid  = tid >> 6;
    const int l16  = lane & 15;
    const int g    = lane >> 4;
    const int wrb  = (BN == 128) ? ((wid >> 1) << 6) : (wid << 5);
    const int wcb  = (BN == 128) ? ((wid & 1) << 6) : 0;
    const int m0   = blockIdx.y << 7;
    const int n0   = blockIdx.x * BN;

    // staging: 16 rows x 64B per instr; source chunk XOR-preswizzled by (row>>1)&3
    const int srow = lane >> 2;
    const int schk = lane & 3;
    const int rA0 = (wid << 5) + srow;
    const int rA1 = rA0 + 16;
    const int rB0 = wid * (BN / 4) + srow;
    const int rB1 = rB0 + 16;
    const bf16* pa0 = A  + (size_t)(m0 + rA0) * K + ((schk ^ ((rA0 >> 1) & 3)) << 3);
    const bf16* pa1 = A  + (size_t)(m0 + rA1) * K + ((schk ^ ((rA1 >> 1) & 3)) << 3);
    const bf16* pb0 = Bt + (size_t)(n0 + rB0) * K + ((schk ^ ((rB0 >> 1) & 3)) << 3);
    const bf16* pb1 = Bt + (size_t)(n0 + rB1) * K + ((schk ^ ((rB1 >> 1) & 3)) << 3);
    const int dA0 = (wid << 5) * BK, dA1 = dA0 + 16 * BK;
    const int dB0 = (wid * (BN / 4)) * BK, dB1 = dB0 + 16 * BK;

    auto issue = [&](bf16* ab, bf16* bb) {
        gl_lds16(pa0, ab + dA0); gl_lds16(pa1, ab + dA1);
        gl_lds16(pb0, bb + dB0);
        if constexpr (BN == 128) gl_lds16(pb1, bb + dB1);
        pa0 += BK; pa1 += BK; pb0 += BK; pb1 += BK;
    };

    // fragment read offsets (elems), swizzle-matched
    int offA[MF], offB[NF];
    #pragma unroll
    for (int mf = 0; mf < MF; ++mf) {
        const int r = wrb + (mf << 4) + l16;
        offA[mf] = r * BK + ((g ^ ((r >> 1) & 3)) << 3);
    }
    #pragma unroll
    for (int nf = 0; nf < NF; ++nf) {
        const int r = wcb + (nf << 4) + l16;
        offB[nf] = r * BK + ((g ^ ((r >> 1) & 3)) << 3);
    }

    f32x4 acc[MF][NF];
    #pragma unroll
    for (int i = 0; i < MF; ++i)
        #pragma unroll
        for (int j = 0; j < NF; ++j) acc[i][j] = zero4();

    const int nk = K >> 5;
    // prologue: stage tiles 0 and 1
    issue(Asb, Bsb);
    issue(Asb + AE, Bsb + BE);

    for (int kt = 0; kt < nk; ++kt) {
        // wait: tile kt's LPI loads (oldest in the in-order vmem queue) complete
        if (kt == nk - 1) {
            asm volatile("s_waitcnt vmcnt(0)" ::: "memory");
        } else {
            if constexpr (LPI == 4) asm volatile("s_waitcnt vmcnt(4)" ::: "memory");
            else                    asm volatile("s_waitcnt vmcnt(3)" ::: "memory");
        }
        __builtin_amdgcn_s_barrier();            // all waves' tile-kt data now in LDS
        const int nxt = kt + 2;
        if (nxt < nk) {                          // prefetch depth 2 into slot (kt+2)%3
            const int s = nxt - (nxt / 3) * 3;
            issue(Asb + s * AE, Bsb + s * BE);
        }
        const int c = kt - (kt / 3) * 3;
        const bf16* ac = Asb + c * AE;
        const bf16* bc = Bsb + c * BE;
        bf16x8 af[MF], bfr[NF];
        #pragma unroll
        for (int mf = 0; mf < MF; ++mf) af[mf] = *(const bf16x8*)&ac[offA[mf]];
        #pragma unroll
        for (int nf = 0; nf < NF; ++nf) bfr[nf] = *(const bf16x8*)&bc[offB[nf]];
        __builtin_amdgcn_s_setprio(1);
        #pragma unroll
        for (int mf = 0; mf < MF; ++mf)
            #pragma unroll
            for (int nf = 0; nf < NF; ++nf)
                acc[mf][nf] = MFMA16(af[mf], bfr[nf], acc[mf][nf]);
        __builtin_amdgcn_s_setprio(0);
    }
    __syncthreads();                             // all reads done before smem reuse

    if (MODE == 0) {
        // ---- LDS-pack epilogue: 128x128 bf16 tile reusing smem ----
        bf16* const Es = smem;
        const int bq  = m0 >> 10;
        const int tb  = m0 & 1023;               // time index within batch
        const int hh0 = (n0 & 1023) >> 6;
        const bool isV = (n0 >= 2048);
        if (isV) {
            #pragma unroll
            for (int mf = 0; mf < MF; ++mf)
                #pragma unroll
                for (int nf = 0; nf < NF; ++nf) {
                    const int nn = wcb + (nf << 4) + l16;
                    const float bs = bias[n0 + nn];
                    bf16x4 p;
                    #pragma unroll
                    for (int j = 0; j < 4; ++j) p[j] = (bf16)(acc[mf][nf][j] + bs);
                    // transposed + PV-kmap permuted: t = 32s+16h+4g'+j -> pos 32s+8g'+4h+j
                    const int m = wrb + (mf << 4) + (g << 2);
                    const int pp = ((m >> 5) << 5) + (((m >> 2) & 3) << 3) + (((m >> 4) & 1) << 2);
                    *(bf16x4*)&Es[nn * 128 + pp] = p;
                }
        } else {
            #pragma unroll
            for (int mf = 0; mf < MF; ++mf)
                #pragma unroll
                for (int nf = 0; nf < NF; ++nf) {
                    const int nn = wcb + (nf << 4) + l16;
                    const float bs = bias[n0 + nn];
                    #pragma unroll
                    for (int j = 0; j < 4; ++j) {
                        const int mm = wrb + (mf << 4) + (g << 2) + j;
                        Es[mm * 128 + nn] = (bf16)(acc[mf][nf][j] + bs);
                    }
                }
        }
        __syncthreads();
        #pragma unroll
        for (int it = 0; it < 8; ++it) {
            const int idx = (it << 8) + tid;
            const int row = idx >> 4, ch = idx & 15;
            const bf16x8 v = *(const bf16x8*)&Es[row * 128 + (ch << 3)];
            if (isV) {
                const int dd = row & 63, hh = hh0 + (row >> 6);
                *(bf16x8*)(vw + ((size_t)((bq << 4) + hh) << 16) + ((size_t)dd << 10)
                           + tb + (ch << 3)) = v;
            } else {
                const int t = tb + row;
                const int cc = ch << 3;
                const int hh = hh0 + (cc >> 6);
                bf16* const dst = (n0 < 1024) ? qw : kw;
                *(bf16x8*)(dst + ((size_t)((bq << 4) + hh) << 16) + ((size_t)t << 6)
                           + (cc & 63)) = v;
            }
        }
    } else {
        #pragma unroll
        for (int mf = 0; mf < MF; ++mf)
            #pragma unroll
            for (int nf = 0; nf < NF; ++nf) {
                const int ng = n0 + wcb + (nf << 4) + l16;
                const float bs = bias[ng];
                #pragma unroll
                for (int j = 0; j < 4; ++j) {
                    const int mg = m0 + wrb + (mf << 4) + (g << 2) + j;
                    outf[(size_t)mg * N + ng] = acc[mf][nf][j] + bs;
                }
            }
    }
}

// ---------------- flash attention: swapped-QK^T, in-register softmax ----------------
// Q,K [bh][1024][64]; Vt [bh][64][1024 t-permuted]; out att [4096][1024] bf16.
// grid (64, 8): blockIdx.x = bh so the 8 blocks sharing one head's K/V are 64 apart
// in dispatch order -> same XCD (round-robin) -> K/V stays in that XCD's L2.
// Block by does q-blocks {by, 15-by} of 64 rows -> 17 kv-tiles/block uniform.
__global__ __launch_bounds__(256)
void attn_k(const bf16* __restrict__ Qp, const bf16* __restrict__ Kp,
            const bf16* __restrict__ Vt, bf16* __restrict__ att)
{
    __shared__ __align__(16) bf16 Kl0[64 * 64], Kl1[64 * 64];
    __shared__ __align__(16) bf16 Vl0[64 * 64], Vl1[64 * 64];

    const int bh = blockIdx.x;          // 0..63
    const int bx = blockIdx.y;          // 0..7
    const int b  = bh >> 4, h = bh & 15;

    const int tid  = threadIdx.x;
    const int lane = tid & 63;
    const int wid  = tid >> 6;
    const int g    = lane >> 4;
    const int l16  = lane & 15;
    const int g8   = g << 3;

    const size_t hb = (size_t)bh << 16;
    const bf16* Qh = Qp + hb;
    const bf16* Kh = Kp + hb;
    const bf16* Vh = Vt + hb;

    // staging: 8 rows x 128B per instr; source chunk XOR-preswizzled by row&7
    const int srow = lane >> 3;                    // 0..7
    const int sswz = ((lane & 7) ^ srow) << 3;     // elems
    const int kr0  = (wid << 4) + srow;
    const int kr1  = kr0 + 8;
    const int dst0 = (wid << 4) << 6;
    const int dst1 = ((wid << 4) + 8) << 6;

    // fragment read offsets (elems), swizzle-matched; rows = kv (K) or d (V^T)
    int offKV[2][4];
    #pragma unroll
    for (int ks = 0; ks < 2; ++ks)
        #pragma unroll
        for (int cb = 0; cb < 4; ++cb) {
            const int r = (cb << 4) + l16;
            offKV[ks][cb] = (r << 6) + (((((ks << 2) + g)) ^ (r & 7)) << 3);
        }

    const float QSCALE = 0.125f * 1.44269504f;     // fold 1/sqrt(d) * log2(e)

    for (int pass = 0; pass < 2; ++pass) {
        const int qb = pass ? (15 - bx) : bx;
        const int q0 = qb << 6;

        // hoist Q as B-fragment (col q = l16), pre-scaled
        const bf16* qp = Qh + ((size_t)(q0 + (wid << 4) + l16) << 6) + g8;
        bf16x8 qf0 = *(const bf16x8*)qp;
        bf16x8 qf1 = *(const bf16x8*)(qp + 32);
        #pragma unroll
        for (int e = 0; e < 8; ++e) {
            qf0[e] = (bf16)(QSCALE * (float)qf0[e]);
            qf1[e] = (bf16)(QSCALE * (float)qf1[e]);
        }

        f32x4 acc_o[4];                 // O^T: row d = 16db+4g+j, col q = l16
        float m_r = -1e30f, l_r = 0.f;  // per-lane scalar stats (one q per lane)
        #pragma unroll
        for (int i = 0; i < 4; ++i) acc_o[i] = zero4();

        // prologue: stage kv tile 0 into buf0
        gl_lds16(Kh + ((size_t)kr0 << 6) + sswz, Kl0 + dst0);
        gl_lds16(Kh + ((size_t)kr1 << 6) + sswz, Kl0 + dst1);
        gl_lds16(Vh + ((size_t)kr0 << 10) + sswz, Vl0 + dst0);
        gl_lds16(Vh + ((size_t)kr1 << 10) + sswz, Vl0 + dst1);
        __syncthreads();

        for (int kt = 0; kt <= qb; ++kt) {
            const bool odd = kt & 1;
            if (kt < qb) {                       // prefetch next kv tile
                const int kv1 = (kt + 1) << 6;
                bf16* Kn = odd ? Kl0 : Kl1;
                bf16* Vn = odd ? Vl0 : Vl1;
                gl_lds16(Kh + ((size_t)(kv1 + kr0) << 6) + sswz, Kn + dst0);
                gl_lds16(Kh + ((size_t)(kv1 + kr1) << 6) + sswz, Kn + dst1);
                gl_lds16(Vh + ((size_t)kr0 << 10) + kv1 + sswz, Vn + dst0);
                gl_lds16(Vh + ((size_t)kr1 << 10) + kv1 + sswz, Vn + dst1);
            }
            const bf16* Kc = odd ? Kl1 : Kl0;
            const bf16* Vc = odd ? Vl1 : Vl0;

            // ---- S^T = mfma(K, Q): sacc[cb][j] = S~[kv=16cb+4g+j][q=l16] ----
            f32x4 sacc[4];
            #pragma unroll
            for (int cb = 0; cb < 4; ++cb) sacc[cb] = zero4();
            #pragma unroll
            for (int cb = 0; cb < 4; ++cb) {
                const bf16x8 kf = *(const bf16x8*)&Kc[offKV[0][cb]];
                sacc[cb] = MFMA16(kf, qf0, sacc[cb]);
            }
            #pragma unroll
            for (int cb = 0; cb < 4; ++cb) {
                const bf16x8 kf = *(const bf16x8*)&Kc[offKV[1][cb]];
                sacc[cb] = MFMA16(kf, qf1, sacc[cb]);
            }
            // ---- causal mask on diagonal tile ----
            if (kt == qb) {
                const int qloc = (wid << 4) + l16;
                #pragma unroll
                for (int cb = 0; cb < 4; ++cb) {
                    #pragma unroll
                    for (int j = 0; j < 4; ++j) {
                        const int kvloc = (cb << 4) + (g << 2) + j;
                        if (kvloc > qloc) sacc[cb][j] = -1e30f;
                    }
                }
            }
            // ---- online softmax, exp2 domain, per-lane scalar, defer-max THR=8 ----
            float pm = sacc[0][0];
            #pragma unroll
            for (int cb = 0; cb < 4; ++cb)
                #pragma unroll
                for (int j = 0; j < 4; ++j) pm = fmaxf(pm, sacc[cb][j]);
            pm = fmaxf(pm, __shfl_xor(pm, 16));
            pm = fmaxf(pm, __shfl_xor(pm, 32));
            if (__any(pm > m_r + 8.f)) {
                const float mn = fmaxf(m_r, pm);
                const float sc = __builtin_amdgcn_exp2f(m_r - mn);
                m_r = mn;
                l_r *= sc;
                #pragma unroll
                for (int db = 0; db < 4; ++db)
                    #pragma unroll
                    for (int j = 0; j < 4; ++j) acc_o[db][j] *= sc;
            }
            float rsum = 0.f;
            #pragma unroll
            for (int cb = 0; cb < 4; ++cb)
                #pragma unroll
                for (int j = 0; j < 4; ++j) {
                    const float p = __builtin_amdgcn_exp2f(sacc[cb][j] - m_r);
                    sacc[cb][j] = p;
                    rsum += p;
                }
            rsum += __shfl_xor(rsum, 16);
            rsum += __shfl_xor(rsum, 32);
            l_r += rsum;
            // ---- P^T fragments in-register (k-map: kv = 32ks+16h+4g+j at elem i=4h+j) ----
            bf16x8 pf0, pf1;
            #pragma unroll
            for (int i = 0; i < 8; ++i) {
                pf0[i] = (bf16)sacc[i >> 2][i & 3];
                pf1[i] = (bf16)sacc[2 + (i >> 2)][i & 3];
            }
            // ---- O^T += V^T P^T (V stored t-permuted to match the k-map) ----
            #pragma unroll
            for (int db = 0; db < 4; ++db) {
                const bf16x8 vf = *(const bf16x8*)&Vc[offKV[0][db]];
                acc_o[db] = MFMA16(vf, pf0, acc_o[db]);
            }
            #pragma unroll
            for (int db = 0; db < 4; ++db) {
                const bf16x8 vf = *(const bf16x8*)&Vc[offKV[1][db]];
                acc_o[db] = MFMA16(vf, pf1, acc_o[db]);
            }
            __syncthreads();
        }

        // ---- epilogue: lane owns q-col l16 -> t fixed; d = 16db+4g+j ----
        const float inv_l = 1.f / l_r;
        const int t = q0 + (wid << 4) + l16;
        #pragma unroll
        for (int db = 0; db < 4; ++db) {
            bf16x4 o;
            #pragma unroll
            for (int j = 0; j < 4; ++j) o[j] = (bf16)(acc_o[db][j] * inv_l);
            *(bf16x4*)(att + (((size_t)b << 10) + t) * 1024 + (h << 6) + (db << 4) + (g << 2)) = o;
        }
        __syncthreads();   // all waves done before pass-2 prologue overwrites buf0
    }
}

extern "C" void kernel_launch(void* const* d_in, const int* in_sizes, int n_in,
                              void* d_out, int out_size, void* d_ws, size_t ws_size,
                              hipStream_t stream)
{
    const float* x      = (const float*)d_in[0];
    const float* w_attn = (const float*)d_in[1];
    const float* b_attn = (const float*)d_in[2];
    const float* w_proj = (const float*)d_in[3];
    const float* b_proj = (const float*)d_in[4];
    float* out = (float*)d_out;

    // workspace layout (bf16 elems)
    bf16* xb  = (bf16*)d_ws;                        // [4096][1024]
    bf16* wT  = xb  + (size_t)4096 * 1024;          // [3072][1024]
    bf16* wpT = wT  + (size_t)3072 * 1024;          // [1024][1024]
    bf16* qw  = wpT + (size_t)1024 * 1024;          // [64 bh][1024 t][64 d]
    bf16* kw  = qw  + (size_t)64 * 1024 * 64;       // [64 bh][1024 t][64 d]
    bf16* vw  = kw  + (size_t)64 * 1024 * 64;       // [64 bh][64 d][1024 t']
    bf16* aw  = vw  + (size_t)64 * 1024 * 64;       // [4096][1024]

    conv_k<<<2048, 256, 0, stream>>>(x, xb, 4096 * 1024);
    transp_k<<<dim3(48, 16), 256, 0, stream>>>(w_attn, wT, 1024, 3072);
    transp_k<<<dim3(16, 16), 256, 0, stream>>>(w_proj, wpT, 1024, 1024);

    gemm_bt<0, 128><<<dim3(24, 32), 256, 0, stream>>>(xb, wT, b_attn, qw, kw, vw,
                                                      nullptr, 4096, 3072, 1024);
    attn_k<<<dim3(64, 8), 256, 0, stream>>>(qw, kw, vw, aw);
    gemm_bt<1, 64><<<dim3(16, 32), 256, 0, stream>>>(aw, wpT, b_proj, nullptr, nullptr, nullptr,
                                                     out, 4096, 1024, 1024);
}